// Round 4
// baseline (884.691 us; speedup 1.0000x reference)
//
#include <hip/hip_runtime.h>

typedef short v8s __attribute__((ext_vector_type(8)));
typedef float v4f __attribute__((ext_vector_type(4)));

#define BM 128
#define BN 128
#define BK 64
#define LDS_STRIDE 72  // 64 + 8 pad

__device__ __forceinline__ float b2f(unsigned short u) {
    union { unsigned int i; float f; } x; x.i = ((unsigned int)u) << 16; return x.f;
}
__device__ __forceinline__ unsigned short f2b(float f) {
    union { float f; unsigned int i; } x; x.f = f;
    unsigned int r = x.i + 0x7fffu + ((x.i >> 16) & 1u);
    return (unsigned short)(r >> 16);
}

// load 8 contiguous elements as bf16 octet; F32 -> convert on the fly
template<bool F32>
__device__ __forceinline__ v8s ld8(const void* base, long elemOff) {
    if (F32) {
        const float* f = (const float*)base + elemOff;
        float4 a = *(const float4*)f;
        float4 b = *(const float4*)(f + 4);
        v8s r;
        r[0] = (short)f2b(a.x); r[1] = (short)f2b(a.y);
        r[2] = (short)f2b(a.z); r[3] = (short)f2b(a.w);
        r[4] = (short)f2b(b.x); r[5] = (short)f2b(b.y);
        r[6] = (short)f2b(b.z); r[7] = (short)f2b(b.w);
        return r;
    } else {
        return *(const v8s*)((const unsigned short*)base + elemOff);
    }
}

// Generic MFMA GEMM: C[m,n] = sum_k A[m,k] * BT[n,k]  (+ epilogue)
// A: M x K (lda), BT: N x K (ldb). Internal compute bf16 16x16x32 MFMA.
// Fragment layouts (verified gfx950): A/B-op m(n)=lane&15, k=(lane>>4)*8+j;
// C/D col=lane&15, row=(lane>>4)*4+reg.
// EPI: 0 plain bf16 | 1 transposed bf16 store, batch from gm (512 rows/batch)
//      2 +bias_f32[gm], bf16 store | 3 scores: *scale, mask fill 1e-9, F32 store
//      4 +resid_f32[gm*ldr+gn], bf16 store
template<int EPI, bool BATCH8, bool AF32, bool BF32, bool CF32>
__global__ __launch_bounds__(256)
void gemm_bt(const void* __restrict__ A, int lda, long aSB, long aSH,
             const void* __restrict__ BT, int ldb, long bSB, long bSH,
             void* __restrict__ C, int ldc, long cSB, long cSH,
             int K,
             const float* __restrict__ bias,
             const float* __restrict__ resid, int ldr,
             const int* __restrict__ mask1, const int* __restrict__ mask2,
             float scale)
{
    const int z = blockIdx.z;
    const int b = BATCH8 ? (z >> 3) : z;
    const int h = BATCH8 ? (z & 7) : 0;
    const long aOff = (long)b * aSB + (long)h * aSH;
    const long bOff = (long)b * bSB + (long)h * bSH;

    __shared__ unsigned short As[BM * LDS_STRIDE];
    __shared__ unsigned short Bs[BN * LDS_STRIDE];

    const int tid = threadIdx.x;
    const int wave = tid >> 6, lane = tid & 63;
    const int wm = (wave >> 1) * 64, wn = (wave & 1) * 64;
    const int quad = lane >> 4, l16 = lane & 15;
    const int bm = blockIdx.y * BM, bn = blockIdx.x * BN;

    v4f acc[4][4] = {};

    for (int k0 = 0; k0 < K; k0 += BK) {
#pragma unroll
        for (int p = 0; p < 4; p++) {
            int idx = p * 256 + tid;
            int row = idx >> 3, ch = idx & 7;
            *(v8s*)&As[row * LDS_STRIDE + ch * 8] =
                ld8<AF32>(A, aOff + (long)(bm + row) * lda + k0 + ch * 8);
            *(v8s*)&Bs[row * LDS_STRIDE + ch * 8] =
                ld8<BF32>(BT, bOff + (long)(bn + row) * ldb + k0 + ch * 8);
        }
        __syncthreads();
#pragma unroll
        for (int ks = 0; ks < 2; ks++) {
            v8s af[4], bf[4];
#pragma unroll
            for (int i = 0; i < 4; i++) {
                af[i] = *(const v8s*)&As[(wm + i * 16 + l16) * LDS_STRIDE + ks * 32 + quad * 8];
                bf[i] = *(const v8s*)&Bs[(wn + i * 16 + l16) * LDS_STRIDE + ks * 32 + quad * 8];
            }
#pragma unroll
            for (int i = 0; i < 4; i++)
#pragma unroll
                for (int j = 0; j < 4; j++)
                    acc[i][j] = __builtin_amdgcn_mfma_f32_16x16x32_bf16(af[i], bf[j], acc[i][j], 0, 0, 0);
        }
        __syncthreads();
    }

    unsigned short* Cu = (unsigned short*)C + (long)b * cSB + (long)h * cSH;
    float* Cf = (float*)C + (long)b * cSB + (long)h * cSH;

#pragma unroll
    for (int i = 0; i < 4; i++) {
        int rowbase = wm + i * 16 + quad * 4;
#pragma unroll
        for (int j = 0; j < 4; j++) {
            int gn = bn + wn + j * 16 + l16;
#pragma unroll
            for (int r = 0; r < 4; r++) {
                int gm = bm + rowbase + r;
                float v = acc[i][j][r];
                if (EPI == 0) {
                    Cu[(long)gm * ldc + gn] = f2b(v);
                } else if (EPI == 1) {
                    int bb = gm >> 9, mm = gm & 511;
                    ((unsigned short*)C)[(long)bb * cSB + (long)gn * ldc + mm] = f2b(v);
                } else if (EPI == 2) {
                    Cu[(long)gm * ldc + gn] = f2b(v + bias[gm]);
                } else if (EPI == 3) {
                    float s = v * scale;
                    if (mask1[b * 512 + gm] != 0 || mask2[b * 512 + gn] != 0) s = 1e-9f;
                    Cf[(long)gm * ldc + gn] = s;
                } else if (EPI == 4) {
                    Cu[(long)gm * ldc + gn] = f2b(v + resid[(long)gm * ldr + gn]);
                }
            }
        }
    }
}

// dst[n][k] = bf16(src[k][n]); src f32 K x N, K,N multiples of 32
__global__ void transc_k(const float* __restrict__ src,
                         unsigned short* __restrict__ dst, int K, int N)
{
    __shared__ float t[32][33];
    int kb = blockIdx.y * 32, nb = blockIdx.x * 32;
    int tx = threadIdx.x, ty = threadIdx.y;
#pragma unroll
    for (int i = 0; i < 32; i += 8)
        t[ty + i][tx] = src[(long)(kb + ty + i) * N + nb + tx];
    __syncthreads();
#pragma unroll
    for (int i = 0; i < 32; i += 8)
        dst[(long)(nb + ty + i) * K + kb + tx] = f2b(t[tx][ty + i]);
}

// elementwise f32 -> bf16
__global__ void cvt_k(const float* __restrict__ s, unsigned short* __restrict__ d, int n)
{
    int i = blockIdx.x * 256 + threadIdx.x;
    if (i < n) d[i] = f2b(s[i]);
}

// in-place f32 softmax over rows of 512; one wave per row
__global__ __launch_bounds__(256)
void softmax_f32(float* __restrict__ attn)
{
    long row = (long)blockIdx.x * 4 + (threadIdx.x >> 6);
    int lane = threadIdx.x & 63;
    float* p = attn + row * 512 + lane * 8;
    float4 a = *(float4*)p, b = *(float4*)(p + 4);
    float f[8] = {a.x, a.y, a.z, a.w, b.x, b.y, b.z, b.w};
    float mx = -1e30f;
#pragma unroll
    for (int i = 0; i < 8; i++) mx = fmaxf(mx, f[i]);
#pragma unroll
    for (int o = 32; o > 0; o >>= 1) mx = fmaxf(mx, __shfl_xor(mx, o, 64));
    float s = 0.f;
#pragma unroll
    for (int i = 0; i < 8; i++) { f[i] = __expf(f[i] - mx); s += f[i]; }
#pragma unroll
    for (int o = 32; o > 0; o >>= 1) s += __shfl_xor(s, o, 64);
    float inv = 1.0f / s;
    a = make_float4(f[0] * inv, f[1] * inv, f[2] * inv, f[3] * inv);
    b = make_float4(f[4] * inv, f[5] * inv, f[6] * inv, f[7] * inv);
    *(float4*)p = a; *(float4*)(p + 4) = b;
}

// LayerNorm over rows of 768 (bf16 in, f32 gamma/beta, f32 out) + nan->0
__global__ __launch_bounds__(256)
void ln_k(const unsigned short* __restrict__ x,
          const float* __restrict__ gamma,
          const float* __restrict__ beta,
          float* __restrict__ out)
{
    long row = (long)blockIdx.x * 4 + (threadIdx.x >> 6);
    int lane = threadIdx.x & 63;
    const unsigned short* p = x + row * 768;
    float v[12];
    float s = 0.f, s2 = 0.f;
#pragma unroll
    for (int j = 0; j < 12; j++) {
        v[j] = b2f(p[lane + j * 64]);
        s += v[j]; s2 += v[j] * v[j];
    }
#pragma unroll
    for (int o = 32; o > 0; o >>= 1) { s += __shfl_xor(s, o, 64); s2 += __shfl_xor(s2, o, 64); }
    float mean = s * (1.0f / 768.0f);
    float var = s2 * (1.0f / 768.0f) - mean * mean;
    if (!(var >= 0.f)) var = 0.f;
    float rstd = rsqrtf(var + 1e-6f);
#pragma unroll
    for (int j = 0; j < 12; j++) {
        int c = lane + j * 64;
        float o = (v[j] - mean) * rstd * gamma[c] + beta[c];
        union { float f; unsigned int i; } u; u.f = o;
        if ((u.i & 0x7FFFFFFFu) > 0x7F800000u) u.f = 0.f;  // nan -> 0 (fast-math-proof)
        out[row * 768 + c] = u.f;
    }
}

extern "C" void kernel_launch(void* const* d_in, const int* in_sizes, int n_in,
                              void* d_out, int out_size, void* d_ws, size_t ws_size,
                              hipStream_t stream)
{
    // B=32, L=512, D_EMB=768, D_K=512, D_V=1024, H=8 — all I/O float32
    const float* q     = (const float*)d_in[0];
    const float* k     = (const float*)d_in[1];
    const float* v     = (const float*)d_in[2];
    const float* Wq    = (const float*)d_in[3];
    const float* Wk    = (const float*)d_in[4];
    const float* Wv    = (const float*)d_in[5];
    const float* Wconv = (const float*)d_in[6];
    const float* bconv = (const float*)d_in[7];
    const float* Wfc   = (const float*)d_in[8];
    const float* gamma = (const float*)d_in[9];
    const float* beta  = (const float*)d_in[10];
    const int* mask1   = (const int*)d_in[11];
    const int* mask2   = (const int*)d_in[12];

    float* out  = (float*)d_out;               // (32,512,768) f32
    float* attn = out + 12582912;              // (32,8,512,512) f32

    // ws layout (ushort elems), peak 36,175,872 = 72.4 MB
    unsigned short* ws = (unsigned short*)d_ws;
    unsigned short* WqT     = ws;              // 512x768
    unsigned short* WkT     = ws + 393216;     // 512x768
    unsigned short* WvT     = ws + 786432;     // 1024x768
    unsigned short* WfcT    = ws + 1572864;    // 768x1024
    unsigned short* Wconv_b = ws + 2359296;    // 512x512
    unsigned short* q1c     = ws + 2621440;    // (32,512,512)
    unsigned short* k1c     = ws + 11010048;   // (32,512,512)
    unsigned short* v1t     = ws + 19398656;   // (32,1024,512)  [.. 36175872)
    unsigned short* out1    = ws + 2621440;    // (32,512,1024) aliases q1c+k1c (dead after scores)
    unsigned short* out2    = ws + 19398656;   // (32,512,768)  aliases v1t   (dead after PV)

    // q1t/k1t: bf16 scratch inside d_out's attn region (f32, 268 MB) — dead before scores
    unsigned short* q1t = (unsigned short*)attn;            // (32,512,512) feature-major
    unsigned short* k1t = (unsigned short*)attn + 8388608;  // (32,512,512)

    dim3 tb(32, 8);
    transc_k<<<dim3(16, 24), tb, 0, stream>>>(Wq, WqT, 768, 512);
    transc_k<<<dim3(16, 24), tb, 0, stream>>>(Wk, WkT, 768, 512);
    transc_k<<<dim3(32, 24), tb, 0, stream>>>(Wv, WvT, 768, 1024);
    transc_k<<<dim3(24, 32), tb, 0, stream>>>(Wfc, WfcT, 1024, 768);
    cvt_k<<<1024, 256, 0, stream>>>(Wconv, Wconv_b, 262144);

    const float scale = 0.04419417382415922f;  // 1/sqrt(512)

    // projections: A f32, B bf16, C bf16 transposed per-batch (feature-major)
    gemm_bt<1, false, true, false, false><<<dim3(4, 128, 1), 256, 0, stream>>>(
        q, 768, 0, 0, WqT, 768, 0, 0, q1t, 512, 262144, 0, 768,
        nullptr, nullptr, 0, nullptr, nullptr, 0.f);
    gemm_bt<1, false, true, false, false><<<dim3(4, 128, 1), 256, 0, stream>>>(
        k, 768, 0, 0, WkT, 768, 0, 0, k1t, 512, 262144, 0, 768,
        nullptr, nullptr, 0, nullptr, nullptr, 0.f);
    gemm_bt<1, false, true, false, false><<<dim3(8, 128, 1), 256, 0, stream>>>(
        v, 768, 0, 0, WvT, 768, 0, 0, v1t, 512, 524288, 0, 768,
        nullptr, nullptr, 0, nullptr, nullptr, 0.f);

    // conv over seq axis: q1c[b][o][l] = sum_c Wconv[o][c]*q1t[b][l-col? (feature-major)] + bconv[o]
    gemm_bt<2, false, false, false, false><<<dim3(4, 4, 32), 256, 0, stream>>>(
        Wconv_b, 512, 0, 0, q1t, 512, 262144, 0, q1c, 512, 262144, 0, 512,
        bconv, nullptr, 0, nullptr, nullptr, 0.f);
    gemm_bt<2, false, false, false, false><<<dim3(4, 4, 32), 256, 0, stream>>>(
        Wconv_b, 512, 0, 0, k1t, 512, 262144, 0, k1c, 512, 262144, 0, 512,
        bconv, nullptr, 0, nullptr, nullptr, 0.f);

    // scores -> masked, scaled, f32 into d_out attn region (q1t/k1t dead from here)
    gemm_bt<3, true, false, false, true><<<dim3(4, 4, 256), 256, 0, stream>>>(
        q1c, 512, 262144, 64, k1c, 512, 262144, 64,
        attn, 512, 2097152, 262144, 64,
        nullptr, nullptr, 0, mask1, mask2, scale);

    // softmax in-place on f32 attn (32*8*512 rows)
    softmax_f32<<<32768, 256, 0, stream>>>(attn);

    // PV: A = f32 attn (stage-convert), B = bf16 v1t
    gemm_bt<0, true, true, false, false><<<dim3(1, 4, 256), 256, 0, stream>>>(
        attn, 512, 2097152, 262144, v1t, 512, 524288, 65536,
        out1, 1024, 524288, 128, 512,
        nullptr, nullptr, 0, nullptr, nullptr, 0.f);

    // FC + f32 residual
    gemm_bt<4, false, false, false, false><<<dim3(6, 128, 1), 256, 0, stream>>>(
        out1, 1024, 0, 0, WfcT, 1024, 0, 0, out2, 768, 0, 0, 1024,
        nullptr, q, 768, nullptr, nullptr, 0.f);

    // LayerNorm + nan->0 -> f32 d_out
    ln_k<<<4096, 256, 0, stream>>>(out2, gamma, beta, out);
}

// Round 5
// 795.453 us; speedup vs baseline: 1.1122x; 1.1122x over previous
//
#include <hip/hip_runtime.h>

typedef short v8s __attribute__((ext_vector_type(8)));
typedef float v4f __attribute__((ext_vector_type(4)));

#define BM 128
#define BN 128
#define BK 64
#define LDS_STRIDE 72  // 64 + 8 pad

__device__ __forceinline__ float b2f(unsigned short u) {
    union { unsigned int i; float f; } x; x.i = ((unsigned int)u) << 16; return x.f;
}
__device__ __forceinline__ unsigned short f2b(float f) {
    union { float f; unsigned int i; } x; x.f = f;
    unsigned int r = x.i + 0x7fffu + ((x.i >> 16) & 1u);
    return (unsigned short)(r >> 16);
}

// load 8 contiguous elements as bf16 octet; F32 -> convert on the fly
template<bool F32>
__device__ __forceinline__ v8s ld8(const void* base, long elemOff) {
    if (F32) {
        const float* f = (const float*)base + elemOff;
        float4 a = *(const float4*)f;
        float4 b = *(const float4*)(f + 4);
        v8s r;
        r[0] = (short)f2b(a.x); r[1] = (short)f2b(a.y);
        r[2] = (short)f2b(a.z); r[3] = (short)f2b(a.w);
        r[4] = (short)f2b(b.x); r[5] = (short)f2b(b.y);
        r[6] = (short)f2b(b.z); r[7] = (short)f2b(b.w);
        return r;
    } else {
        return *(const v8s*)((const unsigned short*)base + elemOff);
    }
}

// Generic MFMA GEMM: C[m,n] = sum_k A[m,k] * BT[n,k]  (+ epilogue)
// A: M x K (lda), BT: N x K (ldb). Internal compute bf16 16x16x32 MFMA.
// Fragment layouts (verified gfx950): A/B-op m(n)=lane&15, k=(lane>>4)*8+j;
// C/D col=lane&15, row=(lane>>4)*4+reg.
// EPI: 0 plain bf16 | 1 transposed bf16 store, batch from gm (512 rows/batch)
//      2 +bias_f32[gm], bf16 store | 4 +resid_f32[gm*ldr+gn], bf16 store
template<int EPI, bool BATCH8, bool AF32, bool BF32>
__global__ __launch_bounds__(256)
void gemm_bt(const void* __restrict__ A, int lda, long aSB, long aSH,
             const void* __restrict__ BT, int ldb, long bSB, long bSH,
             void* __restrict__ C, int ldc, long cSB, long cSH,
             int K,
             const float* __restrict__ bias,
             const float* __restrict__ resid, int ldr)
{
    const int z = blockIdx.z;
    const int b = BATCH8 ? (z >> 3) : z;
    const int h = BATCH8 ? (z & 7) : 0;
    const long aOff = (long)b * aSB + (long)h * aSH;
    const long bOff = (long)b * bSB + (long)h * bSH;

    __shared__ unsigned short As[BM * LDS_STRIDE];
    __shared__ unsigned short Bs[BN * LDS_STRIDE];

    const int tid = threadIdx.x;
    const int wave = tid >> 6, lane = tid & 63;
    const int wm = (wave >> 1) * 64, wn = (wave & 1) * 64;
    const int quad = lane >> 4, l16 = lane & 15;
    const int bm = blockIdx.y * BM, bn = blockIdx.x * BN;

    v4f acc[4][4] = {};

    for (int k0 = 0; k0 < K; k0 += BK) {
#pragma unroll
        for (int p = 0; p < 4; p++) {
            int idx = p * 256 + tid;
            int row = idx >> 3, ch = idx & 7;
            *(v8s*)&As[row * LDS_STRIDE + ch * 8] =
                ld8<AF32>(A, aOff + (long)(bm + row) * lda + k0 + ch * 8);
            *(v8s*)&Bs[row * LDS_STRIDE + ch * 8] =
                ld8<BF32>(BT, bOff + (long)(bn + row) * ldb + k0 + ch * 8);
        }
        __syncthreads();
#pragma unroll
        for (int ks = 0; ks < 2; ks++) {
            v8s af[4], bf[4];
#pragma unroll
            for (int i = 0; i < 4; i++) {
                af[i] = *(const v8s*)&As[(wm + i * 16 + l16) * LDS_STRIDE + ks * 32 + quad * 8];
                bf[i] = *(const v8s*)&Bs[(wn + i * 16 + l16) * LDS_STRIDE + ks * 32 + quad * 8];
            }
#pragma unroll
            for (int i = 0; i < 4; i++)
#pragma unroll
                for (int j = 0; j < 4; j++)
                    acc[i][j] = __builtin_amdgcn_mfma_f32_16x16x32_bf16(af[i], bf[j], acc[i][j], 0, 0, 0);
        }
        __syncthreads();
    }

    unsigned short* Cu = (unsigned short*)C + (long)b * cSB + (long)h * cSH;

#pragma unroll
    for (int i = 0; i < 4; i++) {
        int rowbase = wm + i * 16 + quad * 4;
#pragma unroll
        for (int j = 0; j < 4; j++) {
            int gn = bn + wn + j * 16 + l16;
#pragma unroll
            for (int r = 0; r < 4; r++) {
                int gm = bm + rowbase + r;
                float v = acc[i][j][r];
                if (EPI == 0) {
                    Cu[(long)gm * ldc + gn] = f2b(v);
                } else if (EPI == 1) {
                    int bb = gm >> 9, mm = gm & 511;
                    ((unsigned short*)C)[(long)bb * cSB + (long)gn * ldc + mm] = f2b(v);
                } else if (EPI == 2) {
                    Cu[(long)gm * ldc + gn] = f2b(v + bias[gm]);
                } else if (EPI == 4) {
                    Cu[(long)gm * ldc + gn] = f2b(v + resid[(long)gm * ldr + gn]);
                }
            }
        }
    }
}

// Fused scores + mask + scale + softmax. One block = 128 Q-rows x all 512 K-cols
// for one (b,h). 8 waves x 16 rows. Writes normalized attn f32 exactly once.
__global__ __launch_bounds__(512)
void scores_softmax_k(const unsigned short* __restrict__ q1c,
                      const unsigned short* __restrict__ k1c,
                      float* __restrict__ attn,
                      const int* __restrict__ mask1,
                      const int* __restrict__ mask2,
                      float scale)
{
    const int z = blockIdx.z;
    const int b = z >> 3, h = z & 7;
    const unsigned short* Qb = q1c + (long)b * 262144 + h * 64;  // (512 seq, 512 feat)
    const unsigned short* Kb = k1c + (long)b * 262144 + h * 64;
    float* Ab = attn + (long)z * 262144;

    __shared__ unsigned short Qs[128 * 72];   // 18 KB
    __shared__ unsigned short Ks[512 * 72];   // 72 KB
    __shared__ int m2s[512];                  // 2 KB

    const int tid = threadIdx.x;
    const int wave = tid >> 6, lane = tid & 63;
    const int quad = lane >> 4, l16 = lane & 15;
    const int bm = blockIdx.x * 128;

#pragma unroll
    for (int p = 0; p < 2; p++) {
        int idx = p * 512 + tid;
        int row = idx >> 3, ch = idx & 7;
        *(v8s*)&Qs[row * 72 + ch * 8] = *(const v8s*)&Qb[(long)(bm + row) * 512 + ch * 8];
    }
#pragma unroll
    for (int p = 0; p < 8; p++) {
        int idx = p * 512 + tid;
        int row = idx >> 3, ch = idx & 7;
        *(v8s*)&Ks[row * 72 + ch * 8] = *(const v8s*)&Kb[(long)row * 512 + ch * 8];
    }
    m2s[tid] = mask2[b * 512 + tid];
    __syncthreads();

    const int wrow = wave * 16;
    v8s af0 = *(const v8s*)&Qs[(wrow + l16) * 72 + quad * 8];
    v8s af1 = *(const v8s*)&Qs[(wrow + l16) * 72 + 32 + quad * 8];

    v4f acc[32];
#pragma unroll
    for (int j = 0; j < 32; j++) acc[j] = (v4f){0.f, 0.f, 0.f, 0.f};
#pragma unroll
    for (int j = 0; j < 32; j++) {
        v8s bf0 = *(const v8s*)&Ks[(j * 16 + l16) * 72 + quad * 8];
        v8s bf1 = *(const v8s*)&Ks[(j * 16 + l16) * 72 + 32 + quad * 8];
        acc[j] = __builtin_amdgcn_mfma_f32_16x16x32_bf16(af0, bf0, acc[j], 0, 0, 0);
        acc[j] = __builtin_amdgcn_mfma_f32_16x16x32_bf16(af1, bf1, acc[j], 0, 0, 0);
    }

    // mask + scale (C-layout: row = quad*4+r entirely within one l16 group)
    int m1r[4];
#pragma unroll
    for (int r = 0; r < 4; r++)
        m1r[r] = mask1[b * 512 + bm + wrow + quad * 4 + r];

    float mx[4] = {-1e30f, -1e30f, -1e30f, -1e30f};
#pragma unroll
    for (int j = 0; j < 32; j++) {
        int colm = m2s[j * 16 + l16];
#pragma unroll
        for (int r = 0; r < 4; r++) {
            float s = acc[j][r] * scale;
            if (m1r[r] != 0 || colm != 0) s = 1e-9f;
            acc[j][r] = s;
            mx[r] = fmaxf(mx[r], s);
        }
    }
#pragma unroll
    for (int off = 1; off < 16; off <<= 1)
#pragma unroll
        for (int r = 0; r < 4; r++)
            mx[r] = fmaxf(mx[r], __shfl_xor(mx[r], off, 64));

    float sum[4] = {0.f, 0.f, 0.f, 0.f};
#pragma unroll
    for (int j = 0; j < 32; j++)
#pragma unroll
        for (int r = 0; r < 4; r++) {
            float e = __expf(acc[j][r] - mx[r]);
            acc[j][r] = e;
            sum[r] += e;
        }
#pragma unroll
    for (int off = 1; off < 16; off <<= 1)
#pragma unroll
        for (int r = 0; r < 4; r++)
            sum[r] += __shfl_xor(sum[r], off, 64);

    float inv[4];
#pragma unroll
    for (int r = 0; r < 4; r++) inv[r] = 1.0f / sum[r];

#pragma unroll
    for (int j = 0; j < 32; j++)
#pragma unroll
        for (int r = 0; r < 4; r++)
            Ab[(long)(bm + wrow + quad * 4 + r) * 512 + j * 16 + l16] = acc[j][r] * inv[r];
}

// one segmented kernel for all weight prep: 4 transposes (f32 -> bf16^T) + 1 cast
__global__ __launch_bounds__(256)
void prep_k(const float* __restrict__ Wq, const float* __restrict__ Wk,
            const float* __restrict__ Wv, const float* __restrict__ Wfc,
            const float* __restrict__ Wconv,
            unsigned short* __restrict__ WqT, unsigned short* __restrict__ WkT,
            unsigned short* __restrict__ WvT, unsigned short* __restrict__ WfcT,
            unsigned short* __restrict__ Wconv_b)
{
    __shared__ float t[32][33];
    int blk = blockIdx.x, tid = threadIdx.x;
    if (blk < 2304) {
        const float* src; unsigned short* dst; int K, N, local;
        if (blk < 384)       { src = Wq;  dst = WqT;  K = 768;  N = 512;  local = blk; }
        else if (blk < 768)  { src = Wk;  dst = WkT;  K = 768;  N = 512;  local = blk - 384; }
        else if (blk < 1536) { src = Wv;  dst = WvT;  K = 768;  N = 1024; local = blk - 768; }
        else                 { src = Wfc; dst = WfcT; K = 1024; N = 768;  local = blk - 1536; }
        int nb32 = N >> 5;
        int kb = (local / nb32) * 32, nb = (local % nb32) * 32;
        int tx = tid & 31, ty = tid >> 5;
#pragma unroll
        for (int i = 0; i < 32; i += 8)
            t[ty + i][tx] = src[(long)(kb + ty + i) * N + nb + tx];
        __syncthreads();
#pragma unroll
        for (int i = 0; i < 32; i += 8)
            dst[(long)(nb + ty + i) * K + kb + tx] = f2b(t[tx][ty + i]);
    } else {
        int i = (blk - 2304) * 256 + tid;   // Wconv: 512*512 = 131072... full 262144
        Wconv_b[i] = f2b(Wconv[i]);
    }
}

// LayerNorm over rows of 768 (bf16 in, f32 gamma/beta, f32 out) + nan->0
__global__ __launch_bounds__(256)
void ln_k(const unsigned short* __restrict__ x,
          const float* __restrict__ gamma,
          const float* __restrict__ beta,
          float* __restrict__ out)
{
    long row = (long)blockIdx.x * 4 + (threadIdx.x >> 6);
    int lane = threadIdx.x & 63;
    const unsigned short* p = x + row * 768;
    float v[12];
    float s = 0.f, s2 = 0.f;
#pragma unroll
    for (int j = 0; j < 12; j++) {
        v[j] = b2f(p[lane + j * 64]);
        s += v[j]; s2 += v[j] * v[j];
    }
#pragma unroll
    for (int o = 32; o > 0; o >>= 1) { s += __shfl_xor(s, o, 64); s2 += __shfl_xor(s2, o, 64); }
    float mean = s * (1.0f / 768.0f);
    float var = s2 * (1.0f / 768.0f) - mean * mean;
    if (!(var >= 0.f)) var = 0.f;
    float rstd = rsqrtf(var + 1e-6f);
#pragma unroll
    for (int j = 0; j < 12; j++) {
        int c = lane + j * 64;
        float o = (v[j] - mean) * rstd * gamma[c] + beta[c];
        union { float f; unsigned int i; } u; u.f = o;
        if ((u.i & 0x7FFFFFFFu) > 0x7F800000u) u.f = 0.f;  // nan -> 0 (fast-math-proof)
        out[row * 768 + c] = u.f;
    }
}

extern "C" void kernel_launch(void* const* d_in, const int* in_sizes, int n_in,
                              void* d_out, int out_size, void* d_ws, size_t ws_size,
                              hipStream_t stream)
{
    // B=32, L=512, D_EMB=768, D_K=512, D_V=1024, H=8 — all I/O float32
    const float* q     = (const float*)d_in[0];
    const float* k     = (const float*)d_in[1];
    const float* v     = (const float*)d_in[2];
    const float* Wq    = (const float*)d_in[3];
    const float* Wk    = (const float*)d_in[4];
    const float* Wv    = (const float*)d_in[5];
    const float* Wconv = (const float*)d_in[6];
    const float* bconv = (const float*)d_in[7];
    const float* Wfc   = (const float*)d_in[8];
    const float* gamma = (const float*)d_in[9];
    const float* beta  = (const float*)d_in[10];
    const int* mask1   = (const int*)d_in[11];
    const int* mask2   = (const int*)d_in[12];

    float* out  = (float*)d_out;               // (32,512,768) f32
    float* attn = out + 12582912;              // (32,8,512,512) f32

    // ws layout (ushort elems), peak 36,175,872 = 72.4 MB
    unsigned short* ws = (unsigned short*)d_ws;
    unsigned short* WqT     = ws;              // 512x768
    unsigned short* WkT     = ws + 393216;     // 512x768
    unsigned short* WvT     = ws + 786432;     // 1024x768
    unsigned short* WfcT    = ws + 1572864;    // 768x1024
    unsigned short* Wconv_b = ws + 2359296;    // 512x512
    unsigned short* q1c     = ws + 2621440;    // (32,512,512)
    unsigned short* k1c     = ws + 11010048;   // (32,512,512)
    unsigned short* v1t     = ws + 19398656;   // (32,1024,512)  [.. 36175872)
    unsigned short* out1    = ws + 2621440;    // (32,512,1024) aliases q1c+k1c (dead after scores)
    unsigned short* out2    = ws + 19398656;   // (32,512,768)  aliases v1t   (dead after PV)

    // q1t/k1t: bf16 scratch inside d_out's attn region (f32, 268 MB) — dead before scores
    unsigned short* q1t = (unsigned short*)attn;            // (32,512,512) feature-major
    unsigned short* k1t = (unsigned short*)attn + 8388608;  // (32,512,512)

    // all weight prep in one dispatch
    prep_k<<<3328, 256, 0, stream>>>(Wq, Wk, Wv, Wfc, Wconv,
                                     WqT, WkT, WvT, WfcT, Wconv_b);

    const float scale = 0.04419417382415922f;  // 1/sqrt(512)

    // projections: A f32, B bf16, C bf16 transposed per-batch (feature-major)
    gemm_bt<1, false, true, false><<<dim3(4, 128, 1), 256, 0, stream>>>(
        q, 768, 0, 0, WqT, 768, 0, 0, q1t, 512, 262144, 0, 768,
        nullptr, nullptr, 0);
    gemm_bt<1, false, true, false><<<dim3(4, 128, 1), 256, 0, stream>>>(
        k, 768, 0, 0, WkT, 768, 0, 0, k1t, 512, 262144, 0, 768,
        nullptr, nullptr, 0);
    gemm_bt<1, false, true, false><<<dim3(8, 128, 1), 256, 0, stream>>>(
        v, 768, 0, 0, WvT, 768, 0, 0, v1t, 512, 524288, 0, 768,
        nullptr, nullptr, 0);

    // conv over seq axis: q1c[b] = Wconv_b (o x c) x q1t[b]^T + bconv
    gemm_bt<2, false, false, false><<<dim3(4, 4, 32), 256, 0, stream>>>(
        Wconv_b, 512, 0, 0, q1t, 512, 262144, 0, q1c, 512, 262144, 0, 512,
        bconv, nullptr, 0);
    gemm_bt<2, false, false, false><<<dim3(4, 4, 32), 256, 0, stream>>>(
        Wconv_b, 512, 0, 0, k1t, 512, 262144, 0, k1c, 512, 262144, 0, 512,
        bconv, nullptr, 0);

    // fused scores + mask + scale + softmax -> attn f32, written once
    scores_softmax_k<<<dim3(4, 1, 256), 512, 0, stream>>>(
        q1c, k1c, attn, mask1, mask2, scale);

    // PV: A = f32 attn (stage-convert), B = bf16 v1t
    gemm_bt<0, true, true, false><<<dim3(1, 4, 256), 256, 0, stream>>>(
        attn, 512, 2097152, 262144, v1t, 512, 524288, 65536,
        out1, 1024, 524288, 128, 512,
        nullptr, nullptr, 0);

    // FC + f32 residual
    gemm_bt<4, false, false, false><<<dim3(6, 128, 1), 256, 0, stream>>>(
        out1, 1024, 0, 0, WfcT, 1024, 0, 0, out2, 768, 0, 0, 1024,
        nullptr, q, 768);

    // LayerNorm + nan->0 -> f32 d_out
    ln_k<<<4096, 256, 0, stream>>>(out2, gamma, beta, out);
}